// Round 15
// baseline (29.131 us; speedup 1.0000x reference)
//
#include <hip/hip_runtime.h>
#include <math.h>

#define TAIL_B 20.0f
#define BATCH 16384
#define NELEM (BATCH * 512)   // 8,388,608 elements per output tensor
#define ROWS_PB 64            // rows per block -> 256 blocks = 1 per CU
#define LDS_BYTES 135168      // cumw(34.8K) + cumh(34.8K) + dkpairs(65.5K)

typedef float vf4 __attribute__((ext_vector_type(4)));
typedef float vf2 __attribute__((ext_vector_type(2)));

// Dynamic LDS layout (float offsets):
//   cumw [512][17] @ 0      knot x, stride 17
//   cumh [512][17] @ 8704   knot y
//   dkp  [512][16] float2 @ 17408  (dk[k], dk[k+1]) at slot k ^ (col&15)
__global__ __launch_bounds__(1024, 4) void rqs_fused(
    const float* __restrict__ x, const float* __restrict__ W,
    const float* __restrict__ H, const float* __restrict__ D,
    float* __restrict__ out)
{
    extern __shared__ float s[];
    float* sCW = s;
    float* sCH = s + 8704;
    vf2*   sDP = reinterpret_cast<vf2*>(s + 17408);

    const int tid   = threadIdx.x;
    const int c2    = tid & 255;          // column-pair index
    const int cb    = c2 * 2;             // base column (even)
    const int rslot = tid >> 8;           // 0..3
    const int rbase = blockIdx.x * ROWS_PB + rslot;   // rows: rbase + 16c + 4i

    // ---- chunk-0 prefetch (before prologue) ----
    vf2 xA[4], xB[4];
#pragma unroll
    for (int i = 0; i < 4; ++i)
        xA[i] = *reinterpret_cast<const vf2*>(x + (rbase + 4 * i) * 512 + cb);

    // ---- prologue: 2 threads per column, runs ONCE per CU ----
    {
        const int c    = tid >> 1;        // 0..511 (column this thread builds)
        const int half = tid & 1;         // bins 8*half .. 8*half+7
        const float* Wg = W + c * 16 + half * 8;
        const float* Hg = H + c * 16 + half * 8;

        vf4 wa = *reinterpret_cast<const vf4*>(Wg);
        vf4 wb = *reinterpret_cast<const vf4*>(Wg + 4);
        vf4 ha = *reinterpret_cast<const vf4*>(Hg);
        vf4 hb = *reinterpret_cast<const vf4*>(Hg + 4);

        float mw = fmaxf(fmaxf(fmaxf(wa.x, wa.y), fmaxf(wa.z, wa.w)),
                         fmaxf(fmaxf(wb.x, wb.y), fmaxf(wb.z, wb.w)));
        float mh = fmaxf(fmaxf(fmaxf(ha.x, ha.y), fmaxf(ha.z, ha.w)),
                         fmaxf(fmaxf(hb.x, hb.y), fmaxf(hb.z, hb.w)));
        mw = fmaxf(mw, __shfl_xor(mw, 1));
        mh = fmaxf(mh, __shfl_xor(mh, 1));

        float ew[8] = {__expf(wa.x - mw), __expf(wa.y - mw), __expf(wa.z - mw), __expf(wa.w - mw),
                       __expf(wb.x - mw), __expf(wb.y - mw), __expf(wb.z - mw), __expf(wb.w - mw)};
        float eh[8] = {__expf(ha.x - mh), __expf(ha.y - mh), __expf(ha.z - mh), __expf(ha.w - mh),
                       __expf(hb.x - mh), __expf(hb.y - mh), __expf(hb.z - mh), __expf(hb.w - mh)};

        float sw = 0.0f, sh = 0.0f;
#pragma unroll
        for (int j = 0; j < 8; ++j) { sw += ew[j]; sh += eh[j]; }
        float swp = __shfl_xor(sw, 1), shp = __shfl_xor(sh, 1);
        float scw = (2.0f * TAIL_B) / (sw + swp);
        float sch = (2.0f * TAIL_B) / (sh + shp);

        float aw = half ? swp : 0.0f;     // exclusive prefix from partner
        float ah = half ? shp : 0.0f;

        const float* Dg = D + c * 15;
        float* cw = sCW + c * 17;
        float* ch = sCH + c * 17;
        vf2*   dp = sDP + c * 16;
        if (!half) { cw[0] = -TAIL_B; ch[0] = -TAIL_B; }

        float dk[9];
#pragma unroll
        for (int j = 0; j < 9; ++j) {
            int t = half * 8 + j;         // knot index 0..16
            float dv = 1.0f;
            if (t >= 1 && t < 16) {
                float v = Dg[t - 1];      // fast stable softplus
                dv = fmaxf(v, 0.0f) + __logf(1.0f + __expf(-fabsf(v)));
            }
            dk[j] = dv;
        }

#pragma unroll
        for (int j = 0; j < 8; ++j) {
            aw += ew[j]; ah += eh[j];
            int t = half * 8 + j + 1;     // knot index 1..16
            cw[t] = -TAIL_B + aw * scw;
            ch[t] = -TAIL_B + ah * sch;
            int k = half * 8 + j;         // bin index 0..15
            dp[k ^ (c & 15)] = (vf2){dk[j], dk[j + 1]};
        }
    }
    __syncthreads();

    // interior knots for BOTH owned columns -> registers
    float kr0[15], kr1[15];
#pragma unroll
    for (int t = 0; t < 15; ++t) kr0[t] = sCW[cb * 17 + 1 + t];
#pragma unroll
    for (int t = 0; t < 15; ++t) kr1[t] = sCW[(cb + 1) * 17 + 1 + t];
    const int csw0 = cb & 15;
    const int csw1 = (cb + 1) & 15;

    auto evalc = [&](float xx, const float (&kr)[15], int col, int csw,
                     float& z, float& ld) {
        bool  inside = (xx >= -TAIL_B) && (xx <= TAIL_B);
        float xc = fminf(fmaxf(xx, -TAIL_B), TAIL_B);
        int idx = 0;
#pragma unroll
        for (int t = 0; t < 15; ++t) idx += (xc >= kr[t]) ? 1 : 0;

        int p = col * 17 + idx;
        float k0  = sCW[p], k1  = sCW[p + 1];
        float ch0 = sCH[p], ch1 = sCH[p + 1];
        vf2   dd  = sDP[col * 16 + (idx ^ csw)];
        float d0 = dd.x, d1 = dd.y;

        float invw  = __builtin_amdgcn_rcpf(k1 - k0);
        float hh    = ch1 - ch0;
        float de    = hh * invw;
        float theta = (xc - k0) * invw;
        float omt   = 1.0f - theta;
        float tt    = theta * omt;
        float denom = de + (d0 + d1 - 2.0f * de) * tt;
        float rden  = __builtin_amdgcn_rcpf(denom);
        float numer = hh * (de * theta * theta + d0 * tt);
        float zin   = ch0 + numer * rden;
        float dnum  = de * de * (d1 * theta * theta + 2.0f * de * tt + d0 * omt * omt);
        float ldin  = 0.6931471805599453f * __log2f(dnum * rden * rden);

        z  = inside ? zin : xx;
        ld = inside ? ldin : 0.0f;
    };

    auto compute4 = [&](const vf2 (&xv)[4], int c) {
#pragma unroll
        for (int i = 0; i < 4; ++i) {
            int r = rbase + 16 * c + 4 * i;
            float z0, l0, z1, l1;
            evalc(xv[i].x, kr0, cb,     csw0, z0, l0);
            evalc(xv[i].y, kr1, cb + 1, csw1, z1, l1);
            vf2 zq = {z0, z1};
            vf2 lq = {l0, l1};
            __builtin_nontemporal_store(zq, reinterpret_cast<vf2*>(out + r * 512 + cb));
            __builtin_nontemporal_store(lq, reinterpret_cast<vf2*>(out + NELEM + r * 512 + cb));
        }
    };

    // software pipeline over 4 chunks of 4 rows each
#pragma unroll
    for (int i = 0; i < 4; ++i)
        xB[i] = *reinterpret_cast<const vf2*>(x + (rbase + 16 + 4 * i) * 512 + cb);
    compute4(xA, 0);

#pragma unroll
    for (int i = 0; i < 4; ++i)
        xA[i] = *reinterpret_cast<const vf2*>(x + (rbase + 32 + 4 * i) * 512 + cb);
    compute4(xB, 1);

#pragma unroll
    for (int i = 0; i < 4; ++i)
        xB[i] = *reinterpret_cast<const vf2*>(x + (rbase + 48 + 4 * i) * 512 + cb);
    compute4(xA, 2);

    compute4(xB, 3);
}

extern "C" void kernel_launch(void* const* d_in, const int* in_sizes, int n_in,
                              void* d_out, int out_size, void* d_ws, size_t ws_size,
                              hipStream_t stream)
{
    const float* x = (const float*)d_in[0];
    const float* W = (const float*)d_in[1];
    const float* H = (const float*)d_in[2];
    const float* D = (const float*)d_in[3];
    float* out = (float*)d_out;

    hipFuncSetAttribute(reinterpret_cast<const void*>(&rqs_fused),
                        hipFuncAttributeMaxDynamicSharedMemorySize, LDS_BYTES);

    rqs_fused<<<BATCH / ROWS_PB, 1024, LDS_BYTES, stream>>>(x, W, H, D, out);
}